// Round 12
// baseline (125.415 us; speedup 1.0000x reference)
//
#include <hip/hip_runtime.h>

// TCN, last-timestep receptive-field cone. 5 dispatches, split-K partials
// with consumer-side fused reduce (+bias+relu+residual) at staging time.
// No atomics, no memset (plain stores; kernel boundary = coherence).
//   kA: L0 conv x->P0[8][512][11][64]; down conv x->PD[8][512][5][64]
//   kB: L1 conv (stage B1=relu(sum8 P0+b1_0)) -> P1[16][512][5][64]
//   kC: L2 conv (stage H0=relu(relu(sum16 P1+b2_0)+sum8 PD+bd0)) -> P2[16][512][3][64]
//       ocp==0 blocks also store H0f[512][64] = H0 at u=4 (t=1023)
//   kD: L3 conv (stage B2=relu(sum16 P2+b1_1)) -> P3[8][512][64]
//   kE: fc with H1=relu(relu(sum8 P3+b2_1)+H0f) inline
// t-maps (verified rounds 4/10/11): L0 u=t+kk (x t=1011+u); down u=t
// (x t=1015+2u); L1 u=2t+kk; L2 u=t+kk; L3 u=kk; residual = H0 u=4.
// x staged [(c*T+u)*65+b] (padded -> conflict-free write c-fast & read b-fast).

__device__ __forceinline__ float relu(float v) { return fmaxf(v, 0.f); }
__device__ __forceinline__ float4 relu4(float4 v) {
  v.x = fmaxf(v.x, 0.f); v.y = fmaxf(v.y, 0.f);
  v.z = fmaxf(v.z, 0.f); v.w = fmaxf(v.w, 0.f);
  return v;
}
__device__ __forceinline__ float4 add4(float4 a, float4 b) {
  a.x += b.x; a.y += b.y; a.z += b.z; a.w += b.w;
  return a;
}
__device__ __forceinline__ float4 addc4(float4 a, float c) {
  a.x += c; a.y += c; a.z += c; a.w += c;
  return a;
}
#define F4(q) (*(const float4*)(q))

// ===== kA: blocks 0..255 L0 (32 ocp x 8 ks); 256..383 down (16 x 8) =======
__global__ __launch_bounds__(256) void kA(const float* __restrict__ x,
                                          const float* __restrict__ w1_0,
                                          const float* __restrict__ wd0,
                                          float* __restrict__ P0,
                                          float* __restrict__ PD) {
  __shared__ float smem[14288];  // L0: 768 W + 13520 X(padded)
  const int tid = threadIdx.x, lane = tid & 63, wv = tid >> 6;
  if (blockIdx.x < 256) {
    const int ocp = blockIdx.x >> 3, ks = blockIdx.x & 7, oc0 = ocp * 16;
    float* Als = smem;        // [16c][3kk][16oc]
    float* Bls = smem + 768;  // [(c*13+u)*65+b]
    float acc[4][11];
#pragma unroll
    for (int i = 0; i < 4; ++i)
#pragma unroll
      for (int t = 0; t < 11; ++t) acc[i][t] = 0.f;
    for (int ch = 0; ch < 2; ++ch) {
      const int c0 = ks * 32 + ch * 16;
      if (ch) __syncthreads();
      for (int idx = tid; idx < 768; idx += 256) {
        int i = idx / 48, r = idx % 48, c = r / 3, kk = r % 3;
        Als[(c * 3 + kk) * 16 + i] = w1_0[(oc0 + i) * 768 + (c0 + c) * 3 + kk];
      }
      for (int idx = tid; idx < 13312; idx += 256) {
        int c = idx & 15, b = (idx >> 4) & 63, u = idx >> 10;
        Bls[(c * 13 + u) * 65 + b] = x[(b * 1024 + 1011 + u) * 256 + c0 + c];
      }
      __syncthreads();
      for (int c = 0; c < 16; ++c) {
        float bv[13];
#pragma unroll
        for (int u = 0; u < 13; ++u) bv[u] = Bls[(c * 13 + u) * 65 + lane];
        float av[3][4];
#pragma unroll
        for (int kk = 0; kk < 3; ++kk)
          *(float4*)av[kk] = F4(&Als[(c * 3 + kk) * 16 + wv * 4]);
#pragma unroll
        for (int i = 0; i < 4; ++i)
#pragma unroll
          for (int t = 0; t < 11; ++t)
#pragma unroll
            for (int kk = 0; kk < 3; ++kk)
              acc[i][t] += av[kk][i] * bv[t + kk];
      }
    }
#pragma unroll
    for (int i = 0; i < 4; ++i)
#pragma unroll
      for (int t = 0; t < 11; ++t)
        P0[((ks * 512 + oc0 + wv * 4 + i) * 11 + t) * 64 + lane] = acc[i][t];
  } else {
    const int q = blockIdx.x - 256;
    const int ocp = q >> 3, ks = q & 7, oc0 = ocp * 32;
    float* Ad = smem;        // [16c][32oc]
    float* Bd = smem + 512;  // [(c*5+u)*65+b]
    float acc[8][5];
#pragma unroll
    for (int i = 0; i < 8; ++i)
#pragma unroll
      for (int t = 0; t < 5; ++t) acc[i][t] = 0.f;
    for (int ch = 0; ch < 2; ++ch) {
      const int c0 = ks * 32 + ch * 16;
      if (ch) __syncthreads();
      for (int idx = tid; idx < 512; idx += 256) {
        int i = idx & 31, c = idx >> 5;
        Ad[c * 32 + i] = wd0[(oc0 + i) * 256 + c0 + c];
      }
      for (int idx = tid; idx < 5120; idx += 256) {
        int c = idx & 15, b = (idx >> 4) & 63, u = idx >> 10;
        Bd[(c * 5 + u) * 65 + b] = x[(b * 1024 + 1015 + 2 * u) * 256 + c0 + c];
      }
      __syncthreads();
      for (int c = 0; c < 16; ++c) {
        float bv[5];
#pragma unroll
        for (int u = 0; u < 5; ++u) bv[u] = Bd[(c * 5 + u) * 65 + lane];
        float av[8];
        *(float4*)&av[0] = F4(&Ad[c * 32 + wv * 8]);
        *(float4*)&av[4] = F4(&Ad[c * 32 + wv * 8 + 4]);
#pragma unroll
        for (int i = 0; i < 8; ++i)
#pragma unroll
          for (int t = 0; t < 5; ++t) acc[i][t] += av[i] * bv[t];
      }
    }
#pragma unroll
    for (int i = 0; i < 8; ++i)
#pragma unroll
      for (int t = 0; t < 5; ++t)
        PD[((ks * 512 + oc0 + wv * 8 + i) * 5 + t) * 64 + lane] = acc[i][t];
  }
}

// ===== kB: L1 conv (16 ocp x 16 ks), stage B1 = relu(sum8 P0 + b1_0) ======
__global__ __launch_bounds__(256) void kB(const float* __restrict__ P0,
                                          const float* __restrict__ b1_0,
                                          const float* __restrict__ w2_0,
                                          float* __restrict__ P1) {
  __shared__ float smem[12800];  // 1536 W + 11264 B
  const int tid = threadIdx.x, lane = tid & 63, wv = tid >> 6;
  const int ocp = blockIdx.x >> 4, ks = blockIdx.x & 15, oc0 = ocp * 32;
  float* Als = smem;         // [16c][3kk][32oc]
  float* Bls = smem + 1536;  // [(c*11+u)*64+b]
  float acc[8][5];
#pragma unroll
  for (int i = 0; i < 8; ++i)
#pragma unroll
    for (int t = 0; t < 5; ++t) acc[i][t] = 0.f;
  for (int ch = 0; ch < 2; ++ch) {
    const int c0 = ks * 32 + ch * 16;
    if (ch) __syncthreads();
    for (int idx = tid; idx < 1536; idx += 256) {
      int i = idx / 48, r = idx % 48, c = r / 3, kk = r % 3;
      Als[(c * 3 + kk) * 32 + i] = w2_0[(oc0 + i) * 1536 + (c0 + c) * 3 + kk];
    }
    for (int idx = tid; idx < 2816; idx += 256) {  // 16c*11u*16 quads
      int c = idx / 176, r = idx % 176, u = r / 16, b4 = (r & 15) * 4;
      int cc = c0 + c;
      float4 s = {0.f, 0.f, 0.f, 0.f};
#pragma unroll
      for (int p = 0; p < 8; ++p)
        s = add4(s, F4(&P0[((p * 512 + cc) * 11 + u) * 64 + b4]));
      *(float4*)&Bls[(c * 11 + u) * 64 + b4] = relu4(addc4(s, b1_0[cc]));
    }
    __syncthreads();
    for (int c = 0; c < 16; ++c) {
      float bv[11];
#pragma unroll
      for (int u = 0; u < 11; ++u) bv[u] = Bls[(c * 11 + u) * 64 + lane];
      float av[3][8];
#pragma unroll
      for (int kk = 0; kk < 3; ++kk) {
        *(float4*)&av[kk][0] = F4(&Als[(c * 3 + kk) * 32 + wv * 8]);
        *(float4*)&av[kk][4] = F4(&Als[(c * 3 + kk) * 32 + wv * 8 + 4]);
      }
#pragma unroll
      for (int i = 0; i < 8; ++i)
#pragma unroll
        for (int t = 0; t < 5; ++t)
#pragma unroll
          for (int kk = 0; kk < 3; ++kk)
            acc[i][t] += av[kk][i] * bv[2 * t + kk];
    }
  }
#pragma unroll
  for (int i = 0; i < 8; ++i)
#pragma unroll
    for (int t = 0; t < 5; ++t)
      P1[((ks * 512 + oc0 + wv * 8 + i) * 5 + t) * 64 + lane] = acc[i][t];
}

// ===== kC: L2 conv (16 x 16), stage H0 = relu(relu(sum16 P1+b2_0)+sum8 PD+bd0)
__global__ __launch_bounds__(256) void kC(const float* __restrict__ P1,
                                          const float* __restrict__ b2_0,
                                          const float* __restrict__ PD,
                                          const float* __restrict__ bd0,
                                          const float* __restrict__ w1_1,
                                          float* __restrict__ P2,
                                          float* __restrict__ H0f) {
  __shared__ float smem[6656];  // 1536 W + 5120 B
  const int tid = threadIdx.x, lane = tid & 63, wv = tid >> 6;
  const int ocp = blockIdx.x >> 4, ks = blockIdx.x & 15, oc0 = ocp * 32;
  float* Als = smem;
  float* Bls = smem + 1536;  // [(c*5+u)*64+b]
  float acc[8][3];
#pragma unroll
  for (int i = 0; i < 8; ++i)
#pragma unroll
    for (int t = 0; t < 3; ++t) acc[i][t] = 0.f;
  for (int ch = 0; ch < 2; ++ch) {
    const int c0 = ks * 32 + ch * 16;
    if (ch) __syncthreads();
    for (int idx = tid; idx < 1536; idx += 256) {
      int i = idx / 48, r = idx % 48, c = r / 3, kk = r % 3;
      Als[(c * 3 + kk) * 32 + i] = w1_1[(oc0 + i) * 1536 + (c0 + c) * 3 + kk];
    }
    for (int idx = tid; idx < 1280; idx += 256) {  // 16c*5u*16 quads
      int c = idx / 80, r = idx % 80, u = r / 16, b4 = (r & 15) * 4;
      int cc = c0 + c;
      float4 s = {0.f, 0.f, 0.f, 0.f};
#pragma unroll
      for (int p = 0; p < 16; ++p)
        s = add4(s, F4(&P1[((p * 512 + cc) * 5 + u) * 64 + b4]));
      s = relu4(addc4(s, b2_0[cc]));
      float4 d = {0.f, 0.f, 0.f, 0.f};
#pragma unroll
      for (int p = 0; p < 8; ++p)
        d = add4(d, F4(&PD[((p * 512 + cc) * 5 + u) * 64 + b4]));
      s = relu4(addc4(add4(s, d), bd0[cc]));
      *(float4*)&Bls[(c * 5 + u) * 64 + b4] = s;
      if (ocp == 0 && u == 4) *(float4*)&H0f[cc * 64 + b4] = s;
    }
    __syncthreads();
    for (int c = 0; c < 16; ++c) {
      float bv[5];
#pragma unroll
      for (int u = 0; u < 5; ++u) bv[u] = Bls[(c * 5 + u) * 64 + lane];
      float av[3][8];
#pragma unroll
      for (int kk = 0; kk < 3; ++kk) {
        *(float4*)&av[kk][0] = F4(&Als[(c * 3 + kk) * 32 + wv * 8]);
        *(float4*)&av[kk][4] = F4(&Als[(c * 3 + kk) * 32 + wv * 8 + 4]);
      }
#pragma unroll
      for (int i = 0; i < 8; ++i)
#pragma unroll
        for (int t = 0; t < 3; ++t)
#pragma unroll
          for (int kk = 0; kk < 3; ++kk)
            acc[i][t] += av[kk][i] * bv[t + kk];
    }
  }
#pragma unroll
  for (int i = 0; i < 8; ++i)
#pragma unroll
    for (int t = 0; t < 3; ++t)
      P2[((ks * 512 + oc0 + wv * 8 + i) * 3 + t) * 64 + lane] = acc[i][t];
}

// ===== kD: L3 conv (16 ocp x 8 ks, CCH=64), stage B2 = relu(sum16 P2+b1_1) =
__global__ __launch_bounds__(256) void kD(const float* __restrict__ P2,
                                          const float* __restrict__ b1_1,
                                          const float* __restrict__ w2_1,
                                          float* __restrict__ P3) {
  __shared__ float smem[18432];  // 6144 W + 12288 B
  const int tid = threadIdx.x, lane = tid & 63, wv = tid >> 6;
  const int ocp = blockIdx.x >> 3, ks = blockIdx.x & 7, oc0 = ocp * 32;
  const int c0 = ks * 64;
  float* Als = smem;         // [64c][3kk][32oc]
  float* Bls = smem + 6144;  // [(c*3+u)*64+b]
  float acc[8];
#pragma unroll
  for (int i = 0; i < 8; ++i) acc[i] = 0.f;
  for (int idx = tid; idx < 6144; idx += 256) {
    int i = idx / 192, r = idx % 192, c = r / 3, kk = r % 3;
    Als[(c * 3 + kk) * 32 + i] = w2_1[(oc0 + i) * 1536 + (c0 + c) * 3 + kk];
  }
  for (int idx = tid; idx < 3072; idx += 256) {  // 64c*3u*16 quads
    int c = idx / 48, r = idx % 48, u = r / 16, b4 = (r & 15) * 4;
    int cc = c0 + c;
    float4 s = {0.f, 0.f, 0.f, 0.f};
#pragma unroll
    for (int p = 0; p < 16; ++p)
      s = add4(s, F4(&P2[((p * 512 + cc) * 3 + u) * 64 + b4]));
    *(float4*)&Bls[(c * 3 + u) * 64 + b4] = relu4(addc4(s, b1_1[cc]));
  }
  __syncthreads();
  for (int c = 0; c < 64; ++c) {
    float bv[3];
#pragma unroll
    for (int u = 0; u < 3; ++u) bv[u] = Bls[(c * 3 + u) * 64 + lane];
    float av[3][8];
#pragma unroll
    for (int kk = 0; kk < 3; ++kk) {
      *(float4*)&av[kk][0] = F4(&Als[(c * 3 + kk) * 32 + wv * 8]);
      *(float4*)&av[kk][4] = F4(&Als[(c * 3 + kk) * 32 + wv * 8 + 4]);
    }
#pragma unroll
    for (int i = 0; i < 8; ++i)
#pragma unroll
      for (int kk = 0; kk < 3; ++kk) acc[i] += av[kk][i] * bv[kk];
  }
#pragma unroll
  for (int i = 0; i < 8; ++i)
    P3[(ks * 512 + oc0 + wv * 8 + i) * 64 + lane] = acc[i];
}

// ===== kE: fc; H1 = relu(relu(sum8 P3 + b2_1) + H0f) inline ================
__global__ __launch_bounds__(256) void kE(const float* __restrict__ P3,
                                          const float* __restrict__ b2_1,
                                          const float* __restrict__ H0f,
                                          const float* __restrict__ fcw,
                                          const float* __restrict__ fcb,
                                          float* __restrict__ out) {
  const int j = blockIdx.x, tid = threadIdx.x;
  const int lane = tid & 63, wv = tid >> 6;
  __shared__ float red[4][64];
  float partial = (wv == 0) ? fcb[j] : 0.f;
  for (int o = wv * 128; o < wv * 128 + 128; ++o) {
    float s = 0.f;
#pragma unroll
    for (int p = 0; p < 8; ++p) s += P3[(p * 512 + o) * 64 + lane];
    float h1 = relu(relu(s + b2_1[o]) + H0f[o * 64 + lane]);
    partial += fcw[j * 512 + o] * h1;
  }
  red[wv][lane] = partial;
  __syncthreads();
  if (wv == 0)
    out[lane * 36 + j] =
        red[0][lane] + red[1][lane] + red[2][lane] + red[3][lane];
}

extern "C" void kernel_launch(void* const* d_in, const int* in_sizes, int n_in,
                              void* d_out, int out_size, void* d_ws, size_t ws_size,
                              hipStream_t stream) {
  const float* x    = (const float*)d_in[0];
  const float* w1_0 = (const float*)d_in[4];
  const float* b1_0 = (const float*)d_in[5];
  const float* w2_0 = (const float*)d_in[6];
  const float* b2_0 = (const float*)d_in[7];
  const float* wd0  = (const float*)d_in[8];
  const float* bd0  = (const float*)d_in[9];
  const float* w1_1 = (const float*)d_in[10];
  const float* b1_1 = (const float*)d_in[11];
  const float* w2_1 = (const float*)d_in[12];
  const float* b2_1 = (const float*)d_in[13];
  const float* fcw  = (const float*)d_in[14];
  const float* fcb  = (const float*)d_in[15];
  float* out = (float*)d_out;

  float* P0  = (float*)d_ws;       // 8*512*11*64  = 2,883,584
  float* PD  = P0 + 2883584;       // 8*512*5*64   = 1,310,720
  float* P1  = PD + 1310720;       // 16*512*5*64  = 2,621,440
  float* P2  = P1 + 2621440;       // 16*512*3*64  = 1,572,864
  float* P3  = P2 + 1572864;       // 8*512*64     =   262,144
  float* H0f = P3 + 262144;        // 512*64       =    32,768

  kA<<<384, 256, 0, stream>>>(x, w1_0, wd0, P0, PD);
  kB<<<256, 256, 0, stream>>>(P0, b1_0, w2_0, P1);
  kC<<<256, 256, 0, stream>>>(P1, b2_0, PD, bd0, w1_1, P2, H0f);
  kD<<<128, 256, 0, stream>>>(P2, b1_1, w2_1, P3);
  kE<<<36, 256, 0, stream>>>(P3, b2_1, H0f, fcw, fcb, out);
}